// Round 2
// baseline (186.262 us; speedup 1.0000x reference)
//
#include <hip/hip_runtime.h>

// x: (8, 160, 1024, 1) f32 ; W: (1, 7, 1, 32) f32
// y[n,h,w,c] = sum_k x[n,h,w+k-3] * W[k,c]   (SAME pad along w)
// per (n,w,c): m1 = max_h y, m2 = 2nd max, am = argmax_h
// out[n,h,w,c] = y[n,h,w,c] + (h==am ? m2 : m1)

#define WT 16          // w-positions per block
#define BLOCK 256      // 16 w * 16 channel-pairs

__global__ __launch_bounds__(BLOCK)
void pcc_kernel(const float* __restrict__ x,
                const float* __restrict__ Wf,
                float* __restrict__ out) {
    __shared__ float xs[160][WT + 6];

    const int n  = blockIdx.x >> 6;        // 64 w-tiles per n (1024/16)
    const int wt = blockIdx.x & 63;
    const int w0 = wt * WT;
    const int tid = threadIdx.x;

    // ---- stage x[n, 0:160, w0-3 .. w0+WT+2] into LDS (zero-padded) ----
    const float* xn = x + (size_t)n * 160 * 1024;
    for (int idx = tid; idx < 160 * (WT + 6); idx += BLOCK) {
        int row = idx / (WT + 6);
        int col = idx - row * (WT + 6);
        int gw  = w0 - 3 + col;
        float v = 0.f;
        if (gw >= 0 && gw < 1024) v = xn[row * 1024 + gw];
        xs[row][col] = v;
    }
    __syncthreads();

    const int cpair = tid & 15;            // 16 channel-pairs -> c0 = 0,2,..,30
    const int c0    = cpair * 2;
    const int wl    = tid >> 4;            // 0..15 local w

    // weights for my two channels: W[k][c], k-stride 32
    float wg0[7], wg1[7];
#pragma unroll
    for (int k = 0; k < 7; ++k) {
        wg0[k] = Wf[k * 32 + c0];
        wg1[k] = Wf[k * 32 + c0 + 1];
    }

    // ---- pass 1: top-2 + argmax over h ----
    float m1a = -INFINITY, m2a = -INFINITY;
    float m1b = -INFINITY, m2b = -INFINITY;
    int ama = 0, amb = 0;

    for (int h = 0; h < 160; ++h) {
        float xw[7];
#pragma unroll
        for (int j = 0; j < 7; ++j) xw[j] = xs[h][wl + j];
        float ya = 0.f, yb = 0.f;
#pragma unroll
        for (int j = 0; j < 7; ++j) {
            ya = fmaf(xw[j], wg0[j], ya);
            yb = fmaf(xw[j], wg1[j], yb);
        }
        bool ga = ya > m1a;
        m2a = ga ? m1a : fmaxf(m2a, ya);
        m1a = ga ? ya  : m1a;
        ama = ga ? h   : ama;
        bool gb = yb > m1b;
        m2b = gb ? m1b : fmaxf(m2b, yb);
        m1b = gb ? yb  : m1b;
        amb = gb ? h   : amb;
    }

    // ---- pass 2: recompute conv, add max-other, store float2 ----
    float* obase = out + ((size_t)(n * 160) * 1024 + (w0 + wl)) * 32 + c0;
    for (int h = 0; h < 160; ++h) {
        float xw[7];
#pragma unroll
        for (int j = 0; j < 7; ++j) xw[j] = xs[h][wl + j];
        float ya = 0.f, yb = 0.f;
#pragma unroll
        for (int j = 0; j < 7; ++j) {
            ya = fmaf(xw[j], wg0[j], ya);
            yb = fmaf(xw[j], wg1[j], yb);
        }
        float oa = ya + (h == ama ? m2a : m1a);
        float ob = yb + (h == amb ? m2b : m1b);
        float2 v; v.x = oa; v.y = ob;
        *reinterpret_cast<float2*>(obase + (size_t)h * 1024 * 32) = v;
    }
}

extern "C" void kernel_launch(void* const* d_in, const int* in_sizes, int n_in,
                              void* d_out, int out_size, void* d_ws, size_t ws_size,
                              hipStream_t stream) {
    const float* x  = (const float*)d_in[0];   // 8*160*1024
    const float* Wf = (const float*)d_in[1];   // 7*32
    float* out = (float*)d_out;                // 8*160*1024*32
    dim3 grid(8 * (1024 / WT));                // 512 blocks
    dim3 block(BLOCK);
    pcc_kernel<<<grid, block, 0, stream>>>(x, Wf, out);
}

// Round 3
// 185.209 us; speedup vs baseline: 1.0057x; 1.0057x over previous
//
#include <hip/hip_runtime.h>

// x: (8, 160, 1024, 1) f32 ; W: (1, 7, 1, 32) f32
// y[n,h,w,c] = sum_k x[n,h,w+k-3] * W[k,c]   (SAME pad along w)
// per (n,w,c): m1 = max_h y, m2 = 2nd max, am = argmax_h
// out[n,h,w,c] = y[n,h,w,c] + (h==am ? m2 : m1)
//
// R3: 1 channel/thread (32c x 8w = 256 thr), WT=8, 1024 blocks
//     -> 4 waves/SIMD (was 2); #pragma unroll 4 on h-loops to break
//     the ds_read->fma->select dependency chain (latency-bound in R2).

#define WT 8           // w-positions per block
#define BLOCK 256      // 32 channels * 8 w

__global__ __launch_bounds__(BLOCK)
void pcc_kernel(const float* __restrict__ x,
                const float* __restrict__ Wf,
                float* __restrict__ out) {
    __shared__ float xs[160][WT + 6];   // 8960 B

    const int n  = blockIdx.x >> 7;     // 128 w-tiles per n (1024/8)
    const int wt = blockIdx.x & 127;
    const int w0 = wt * WT;
    const int tid = threadIdx.x;

    // ---- stage x[n, 0:160, w0-3 .. w0+WT+2] into LDS (zero-padded) ----
    const float* xn = x + (size_t)n * 160 * 1024;
    for (int idx = tid; idx < 160 * (WT + 6); idx += BLOCK) {
        int row = idx / (WT + 6);
        int col = idx - row * (WT + 6);
        int gw  = w0 - 3 + col;
        float v = 0.f;
        if (gw >= 0 && gw < 1024) v = xn[row * 1024 + gw];
        xs[row][col] = v;
    }
    __syncthreads();

    const int c  = tid & 31;            // channel 0..31
    const int wl = tid >> 5;            // local w 0..7

    float wg[7];
#pragma unroll
    for (int k = 0; k < 7; ++k) wg[k] = Wf[k * 32 + c];

    // ---- pass 1: top-2 + argmax over h ----
    float m1 = -INFINITY, m2 = -INFINITY;
    int am = 0;

#pragma unroll 4
    for (int h = 0; h < 160; ++h) {
        float y = 0.f;
#pragma unroll
        for (int j = 0; j < 7; ++j) y = fmaf(xs[h][wl + j], wg[j], y);
        bool g = y > m1;
        m2 = g ? m1 : fmaxf(m2, y);
        m1 = g ? y  : m1;
        am = g ? h  : am;
    }

    // ---- pass 2: recompute conv, add max-other, store ----
    float* obase = out + ((size_t)(n * 160) * 1024 + (w0 + wl)) * 32 + c;
#pragma unroll 4
    for (int h = 0; h < 160; ++h) {
        float y = 0.f;
#pragma unroll
        for (int j = 0; j < 7; ++j) y = fmaf(xs[h][wl + j], wg[j], y);
        obase[(size_t)h * 1024 * 32] = y + (h == am ? m2 : m1);
    }
}

extern "C" void kernel_launch(void* const* d_in, const int* in_sizes, int n_in,
                              void* d_out, int out_size, void* d_ws, size_t ws_size,
                              hipStream_t stream) {
    const float* x  = (const float*)d_in[0];   // 8*160*1024
    const float* Wf = (const float*)d_in[1];   // 7*32
    float* out = (float*)d_out;                // 8*160*1024*32
    dim3 grid(8 * (1024 / WT));                // 1024 blocks
    dim3 block(BLOCK);
    pcc_kernel<<<grid, block, 0, stream>>>(x, Wf, out);
}